// Round 6
// baseline (420.190 us; speedup 1.0000x reference)
//
#include <hip/hip_runtime.h>
#include <cmath>

typedef unsigned short u16;
typedef __bf16 bf16x8 __attribute__((ext_vector_type(8)));
typedef float f32x4 __attribute__((ext_vector_type(4)));

#define DEVI __device__ __forceinline__

DEVI float b2f(u16 u){ union{unsigned int i; float f;} v; v.i=(unsigned int)u<<16; return v.f; }
DEVI u16 f2b(float f){ union{unsigned int i; float f;} v; v.f=f;
    unsigned int r=(v.i+0x7FFFu+((v.i>>16)&1u))>>16; return (u16)r; }

DEVI void gload_lds16(const u16* g, u16* l){
    __builtin_amdgcn_global_load_lds((__attribute__((address_space(1))) void*)g,
                                     (__attribute__((address_space(3))) void*)l,
                                     16, 0, 0);
}

// ---------------------------------------------------------------------------
// fp32 -> bf16 elementwise (X ingest). 4 elems/thread.
// ---------------------------------------------------------------------------
__global__ __launch_bounds__(256)
void cvt_bf16(const float* __restrict__ in, u16* __restrict__ out)
{
    const int i = (blockIdx.x * 256 + threadIdx.x) * 4;
    float4 v = *(const float4*)&in[i];
    ushort4 o;
    o.x = f2b(v.x); o.y = f2b(v.y); o.z = f2b(v.z); o.w = f2b(v.w);
    *(ushort4*)&out[i] = o;
}

// ---------------------------------------------------------------------------
// fp32 [R,C] -> bf16 [C,R] transpose (weight ingest). 64x64 LDS tiles.
// ---------------------------------------------------------------------------
__global__ __launch_bounds__(256)
void cvt_transpose(const float* __restrict__ in, u16* __restrict__ out, int R, int C)
{
    __shared__ __align__(16) u16 tile[64*72];
    const int rb = blockIdx.x*64, cb = blockIdx.y*64;
    const int t = threadIdx.x;
    const int r = t >> 3, c0 = (t & 7) * 8;
    #pragma unroll
    for (int rr = 0; rr < 2; rr++) {
        const int row = r + rr*32;
        float4 a = *(const float4*)&in[(long)(rb + row)*C + cb + c0];
        float4 b = *(const float4*)&in[(long)(rb + row)*C + cb + c0 + 4];
        u16* tp = &tile[row*72 + c0];
        tp[0]=f2b(a.x); tp[1]=f2b(a.y); tp[2]=f2b(a.z); tp[3]=f2b(a.w);
        tp[4]=f2b(b.x); tp[5]=f2b(b.y); tp[6]=f2b(b.z); tp[7]=f2b(b.w);
    }
    __syncthreads();
    #pragma unroll
    for (int rr = 0; rr < 2; rr++) {
        const int cr = r + rr*32;
        u16 tmp[8];
        #pragma unroll
        for (int j = 0; j < 8; j++) tmp[j] = tile[(c0 + j)*72 + cr];
        *(uint4*)&out[(long)(cb + cr)*R + rb + c0] = *(uint4*)tmp;
    }
}

// ---------------------------------------------------------------------------
// GEMM: C[M,N] = A[M,K] @ Bt[N,K]^T + bias (+ residual | GELU). bf16 in/out,
// fp32 accum. Tile BM x 128, BK=64 (two 32-wide panels). 4 waves.
// EPI: 0 = bias, 1 = bias + residual(bf16), 2 = bias + tanh-GELU.
// ---------------------------------------------------------------------------
template<int EPI, int BM>
__global__ __launch_bounds__(256)
void gemm_bt(const u16* __restrict__ A, const u16* __restrict__ Bt,
             const float* __restrict__ bias, const u16* __restrict__ Res,
             u16* __restrict__ C, int M, int N, int K)
{
    constexpr int RM = BM / 32;
    constexpr int NA = (BM / 16) * 2 / 4;
    __shared__ __align__(16) u16 As[BM*64];
    __shared__ __align__(16) u16 Bs[128*64];
    const int tid  = threadIdx.x;
    const int wave = tid >> 6, lane = tid & 63;
    const int tm = blockIdx.x * BM, tn = blockIdx.y * 128;

    const int rs = lane >> 2, cs = (lane & 3) * 8;
    const u16* gA[NA]; u16* lA[NA];
    #pragma unroll
    for (int i = 0; i < NA; i++) {
        const int c = wave + i*4;
        const int p = c / (BM/16), rb = c % (BM/16);
        gA[i] = A + (long)(tm + rb*16 + rs)*K + p*32 + cs;
        lA[i] = As + p*(BM*32) + rb*512;
    }
    const u16* gB[4]; u16* lB[4];
    #pragma unroll
    for (int i = 0; i < 4; i++) {
        const int c = wave + i*4;
        const int p = c >> 3, rb = c & 7;
        gB[i] = Bt + (long)(tn + rb*16 + rs)*K + p*32 + cs;
        lB[i] = Bs + p*(128*32) + rb*512;
    }

    const int wm = (wave >> 1) * (BM/2), wn = (wave & 1) * 64;
    const int fr = lane & 15, fq = lane >> 4;

    f32x4 acc[RM][4] = {};
    for (int k0 = 0; k0 < K; k0 += 64) {
        __syncthreads();
        #pragma unroll
        for (int i = 0; i < NA; i++) gload_lds16(gA[i] + k0, lA[i]);
        #pragma unroll
        for (int i = 0; i < 4; i++)  gload_lds16(gB[i] + k0, lB[i]);
        __syncthreads();
        #pragma unroll
        for (int p = 0; p < 2; p++) {
            bf16x8 af[RM], bfr[4];
            #pragma unroll
            for (int i = 0; i < RM; i++)
                af[i]  = *(const bf16x8*)&As[p*(BM*32) + (wm + i*16 + fr)*32 + fq*8];
            #pragma unroll
            for (int j = 0; j < 4; j++)
                bfr[j] = *(const bf16x8*)&Bs[p*(128*32) + (wn + j*16 + fr)*32 + fq*8];
            #pragma unroll
            for (int i = 0; i < RM; i++)
                #pragma unroll
                for (int j = 0; j < 4; j++)
                    acc[i][j] = __builtin_amdgcn_mfma_f32_16x16x32_bf16(af[i], bfr[j], acc[i][j], 0, 0, 0);
        }
    }

    #pragma unroll
    for (int i = 0; i < RM; i++) {
        const int row = tm + wm + i*16 + fq*4;
        #pragma unroll
        for (int j = 0; j < 4; j++) {
            const int col = tn + wn + j*16 + fr;
            const float bv = bias[col];
            #pragma unroll
            for (int r = 0; r < 4; r++) {
                float v = acc[i][j][r] + bv;
                const long idx = (long)(row + r)*N + col;
                if (EPI == 1) v += b2f(Res[idx]);
                if (EPI == 2) {
                    const float u = v + 0.044715f*v*v*v;
                    const float t = exp2f(u * 2.302208f);
                    v = v * t * __builtin_amdgcn_rcpf(t + 1.f);
                }
                C[idx] = f2b(v);
            }
        }
    }
}

// ---------------------------------------------------------------------------
// Flash attention v3, causal. block = (qtile64, head, batch); 4 waves x 16 q.
// 128-key K-tiles. S^T = K Q^T (softmax rows per-lane); O^T = V^T P^T so
// alpha/l rescale needs NO cross-lane traffic. P LDS roundtrip per 64-key
// half, overlaid on dead Q staging. Q pre-scaled by 1/sqrt(64).
// LDS: Qs/Ps 9216 + Ks 18432 + Vs 17408 = 45056 B -> 3 blocks/CU.
// ---------------------------------------------------------------------------
__global__ __launch_bounds__(256)
void attn_kernel(const u16* __restrict__ qkv, u16* __restrict__ O)
{
    constexpr float LOG2E = 1.4426950408889634f;
    __shared__ __align__(16) u16 Qs[64*72];      // reused as P after hoist
    __shared__ __align__(16) u16 Ks[128*72];
    __shared__ __align__(16) u16 Vs[64*136];     // V^T, XOR-swizzled

    const int tid = threadIdx.x, wave = tid >> 6, lane = tid & 63;
    const int qt = blockIdx.x, h = blockIdx.y, b = blockIdx.z;
    const long base = (long)b*2048*3072 + h*64;
    const int fr = lane & 15, fq = lane >> 4;

    { // load Q tile once, pre-scaled by 0.125
        const int r = tid >> 3, c = (tid & 7) * 8;
        #pragma unroll
        for (int rr = 0; rr < 2; rr++) {
            uint4 v = *(const uint4*)&qkv[base + (long)(qt*64 + r + rr*32)*3072 + c];
            u16 tmp[8]; *(uint4*)tmp = v;
            u16* qp = &Qs[(r + rr*32)*72 + c];
            #pragma unroll
            for (int j = 0; j < 8; j++) qp[j] = f2b(b2f(tmp[j]) * 0.125f);
        }
    }
    __syncthreads();

    bf16x8 bq[2];
    #pragma unroll
    for (int ks = 0; ks < 2; ks++)
        bq[ks] = *(const bf16x8*)&Qs[(wave*16 + fr)*72 + ks*32 + fq*8];

    const int q_glob = qt*64 + wave*16 + fr;   // this lane's q-row
    const int q_wmin = qt*64 + wave*16;        // wave's smallest q-row
    f32x4 o[4] = {};
    float m_i = -1e30f, l_i = 0.f;
    const int nkt = (qt >> 1) + 1;

    for (int kt = 0; kt < nkt; kt++) {
        const int k0 = kt * 128;
        __syncthreads();   // all waves done with Ks/Vs (and P region from prev)
        { // stage K row-major (stride 72) and V transposed+swizzled (stride 136)
            const int r = tid >> 3, c = (tid & 7) * 8;
            #pragma unroll
            for (int rr = 0; rr < 4; rr++) {
                const int row = r + rr*32;
                uint4 kv = *(const uint4*)&qkv[base + 1024 + (long)(k0 + row)*3072 + c];
                *(uint4*)&Ks[row*72 + c] = kv;
                uint4 vv = *(const uint4*)&qkv[base + 2048 + (long)(k0 + row)*3072 + c];
                u16 tmp[8]; *(uint4*)tmp = vv;
                #pragma unroll
                for (int j = 0; j < 8; j++) {
                    const int d = c + j;
                    Vs[d*136 + (row ^ (d & 56))] = tmp[j];
                }
            }
        }
        __syncthreads();

        // S^T = K Q^T : 8 key-tiles x 16 q
        f32x4 st[8];
        #pragma unroll
        for (int mt = 0; mt < 8; mt++) st[mt] = (f32x4){0.f,0.f,0.f,0.f};
        #pragma unroll
        for (int mt = 0; mt < 8; mt++)
            #pragma unroll
            for (int ks = 0; ks < 2; ks++) {
                bf16x8 ak = *(const bf16x8*)&Ks[(mt*16 + fr)*72 + ks*32 + fq*8];
                st[mt] = __builtin_amdgcn_mfma_f32_16x16x32_bf16(ak, bq[ks], st[mt], 0, 0, 0);
            }

        // mask (only when tile crosses the diagonal for this wave) + max
        float mx = -1e30f;
        if (k0 + 127 > q_wmin) {
            #pragma unroll
            for (int mt = 0; mt < 8; mt++)
                #pragma unroll
                for (int r = 0; r < 4; r++) {
                    const int key = k0 + mt*16 + fq*4 + r;
                    float v = st[mt][r];
                    if (key > q_glob) v = -1e30f;
                    st[mt][r] = v;
                    mx = fmaxf(mx, v);
                }
        } else {
            #pragma unroll
            for (int mt = 0; mt < 8; mt++)
                #pragma unroll
                for (int r = 0; r < 4; r++) mx = fmaxf(mx, st[mt][r]);
        }
        mx = fmaxf(mx, __shfl_xor(mx, 16, 64));
        mx = fmaxf(mx, __shfl_xor(mx, 32, 64));
        const float mnew  = fmaxf(m_i, mx);
        const float alpha = exp2f((m_i - mnew) * LOG2E);
        float ps = 0.f;
        #pragma unroll
        for (int mt = 0; mt < 8; mt++)
            #pragma unroll
            for (int r = 0; r < 4; r++) {
                const float p = exp2f((st[mt][r] - mnew) * LOG2E);
                st[mt][r] = p; ps += p;
            }
        ps += __shfl_xor(ps, 16, 64);
        ps += __shfl_xor(ps, 32, 64);
        l_i = l_i * alpha + ps;
        m_i = mnew;

        // O^T rescale: per-lane alpha (lane fr owns q-row fr) — no shuffles
        #pragma unroll
        for (int dt = 0; dt < 4; dt++)
            #pragma unroll
            for (int r = 0; r < 4; r++) o[dt][r] *= alpha;

        // PV per 64-key half: P -> LDS (A/B-sym layout), O^T += V^T P^T
        u16* pw = &Qs[wave * 1152];           // 16 x 72, overlaid on dead Qs
        #pragma unroll
        for (int half = 0; half < 2; half++) {
            #pragma unroll
            for (int mt2 = 0; mt2 < 4; mt2++)
                #pragma unroll
                for (int d = 0; d < 2; d++) {
                    const int mt = half*4 + mt2;
                    const unsigned pk = (unsigned)f2b(st[mt][2*d]) |
                                        ((unsigned)f2b(st[mt][2*d+1]) << 16);
                    *(unsigned*)&pw[fr*72 + mt2*16 + fq*4 + 2*d] = pk;
                }
            __asm__ volatile("" ::: "memory");
            bf16x8 bp[2];
            #pragma unroll
            for (int kk = 0; kk < 2; kk++)
                bp[kk] = *(const bf16x8*)&pw[fr*72 + kk*32 + fq*8];
            #pragma unroll
            for (int dt = 0; dt < 4; dt++) {
                const int d = dt*16 + fr;
                #pragma unroll
                for (int kk = 0; kk < 2; kk++) {
                    const int kb = (half*64 + kk*32 + fq*8) ^ (d & 56);
                    bf16x8 av = *(const bf16x8*)&Vs[d*136 + kb];
                    o[dt] = __builtin_amdgcn_mfma_f32_16x16x32_bf16(av, bp[kk], o[dt], 0, 0, 0);
                }
            }
            __asm__ volatile("" ::: "memory");
        }
    }

    // epilogue: lane fr owns q-row; pack 4 cols -> 8B stores
    const float rl = __builtin_amdgcn_rcpf(l_i);
    const long orow = (long)b*2048 + qt*64 + wave*16 + fr;
    #pragma unroll
    for (int dt = 0; dt < 4; dt++) {
        u16 pk[4];
        #pragma unroll
        for (int r = 0; r < 4; r++) pk[r] = f2b(o[dt][r] * rl);
        *(uint2*)&O[orow*1024 + h*64 + dt*16 + fq*4] = *(uint2*)pk;
    }
}

// ---------------------------------------------------------------------------
// LayerNorm over 1024 cols; bf16 in, fp32 gamma/beta; OUTF32 selects output.
// ---------------------------------------------------------------------------
template<int OUTF32>
__global__ __launch_bounds__(256)
void ln_kernel(const u16* __restrict__ X, const float* __restrict__ G,
               const float* __restrict__ B, void* __restrict__ Yv)
{
    __shared__ float red[8];
    const int tid = threadIdx.x;
    const long row = blockIdx.x;
    const u16* x = X + row*1024;
    ushort4 u = *(const ushort4*)&x[tid*4];
    const float v0 = b2f(u.x), v1 = b2f(u.y), v2 = b2f(u.z), v3 = b2f(u.w);
    float s = v0+v1+v2+v3;
    float q = v0*v0+v1*v1+v2*v2+v3*v3;
    #pragma unroll
    for (int off = 32; off >= 1; off >>= 1) {
        s += __shfl_xor(s, off, 64);
        q += __shfl_xor(q, off, 64);
    }
    const int wv = tid >> 6;
    if ((tid & 63) == 0) { red[wv*2] = s; red[wv*2+1] = q; }
    __syncthreads();
    s = red[0]+red[2]+red[4]+red[6];
    q = red[1]+red[3]+red[5]+red[7];
    const float mu = s * (1.f/1024.f);
    const float rstd = rsqrtf(fmaxf(q*(1.f/1024.f) - mu*mu, 0.f) + 1e-5f);
    float4 g4 = *(const float4*)&G[tid*4];
    float4 b4 = *(const float4*)&B[tid*4];
    const float y0 = (v0-mu)*rstd*g4.x + b4.x;
    const float y1 = (v1-mu)*rstd*g4.y + b4.y;
    const float y2 = (v2-mu)*rstd*g4.z + b4.z;
    const float y3 = (v3-mu)*rstd*g4.w + b4.w;
    if (OUTF32) {
        float4 o = make_float4(y0, y1, y2, y3);
        *(float4*)&((float*)Yv)[row*1024 + tid*4] = o;
    } else {
        ushort4 o;
        o.x = f2b(y0); o.y = f2b(y1); o.z = f2b(y2); o.w = f2b(y3);
        *(ushort4*)&((u16*)Yv)[row*1024 + tid*4] = o;
    }
}

// ---------------------------------------------------------------------------
// Workspace: 48 MiB of d_ws + d_out (16 MiB) as scratch for W1T/W2T.
// Liveness identical to Round 3 (audited, passed).
// ---------------------------------------------------------------------------
extern "C" void kernel_launch(void* const* d_in, const int* in_sizes, int n_in,
                              void* d_out, int out_size, void* d_ws, size_t ws_size,
                              hipStream_t stream)
{
    const float* X    = (const float*)d_in[0];
    const float* Wqkv = (const float*)d_in[1];
    const float* bqkv = (const float*)d_in[2];
    const float* Wo   = (const float*)d_in[3];
    const float* bo   = (const float*)d_in[4];
    const float* W1   = (const float*)d_in[5];
    const float* b1   = (const float*)d_in[6];
    const float* W2   = (const float*)d_in[7];
    const float* b2   = (const float*)d_in[8];
    const float* g1   = (const float*)d_in[9];
    const float* be1  = (const float*)d_in[10];
    const float* g2   = (const float*)d_in[11];
    const float* be2  = (const float*)d_in[12];
    float* out = (float*)d_out;

    char* ws = (char*)d_ws;
    u16* Xbf   = (u16*)(ws + 0);
    u16* WqkvT = (u16*)(ws + 8388608);
    u16* WoT   = (u16*)(ws + 14680064);
    u16* QKV   = (u16*)(ws + 16777216);
    u16* AO    = (u16*)(ws + 41943040);
    u16* S1    = (u16*)(ws + 16777216);
    u16* H1    = (u16*)(ws + 0);
    u16* Gbuf  = (u16*)(ws + 8388608);
    u16* S2    = (u16*)(ws + 41943040);
    u16* W1T   = (u16*)d_out;                  // 4096x1024 bf16 = 8 MiB
    u16* W2T   = (u16*)d_out + 4194304;        // 1024x4096 bf16 = 8 MiB

    cvt_bf16<<<4096, 256, 0, stream>>>(X, Xbf);
    cvt_transpose<<<dim3(16, 48), 256, 0, stream>>>(Wqkv, WqkvT, 1024, 3072);
    cvt_transpose<<<dim3(16, 16), 256, 0, stream>>>(Wo,   WoT,   1024, 1024);
    cvt_transpose<<<dim3(16, 64), 256, 0, stream>>>(W1,   W1T,   1024, 4096);
    cvt_transpose<<<dim3(64, 16), 256, 0, stream>>>(W2,   W2T,   4096, 1024);

    gemm_bt<0,128><<<dim3(32, 24), 256, 0, stream>>>(Xbf, WqkvT, bqkv, nullptr, QKV, 4096, 3072, 1024);
    attn_kernel<<<dim3(32, 16, 2), 256, 0, stream>>>(QKV, AO);
    gemm_bt<1,64><<<dim3(64, 8), 256, 0, stream>>>(AO, WoT, bo, Xbf, S1, 4096, 1024, 1024);
    ln_kernel<0><<<4096, 256, 0, stream>>>(S1, g1, be1, H1);
    gemm_bt<2,128><<<dim3(32, 32), 256, 0, stream>>>(H1, W1T, b1, nullptr, Gbuf, 4096, 4096, 1024);
    gemm_bt<1,64><<<dim3(64, 8), 256, 0, stream>>>(Gbuf, W2T, b2, H1, S2, 4096, 1024, 4096);
    ln_kernel<1><<<4096, 256, 0, stream>>>(S2, g2, be2, out);
}

// Round 7
// 407.497 us; speedup vs baseline: 1.0312x; 1.0312x over previous
//
#include <hip/hip_runtime.h>
#include <cmath>

typedef unsigned short u16;
typedef __bf16 bf16x8 __attribute__((ext_vector_type(8)));
typedef float f32x4 __attribute__((ext_vector_type(4)));

#define DEVI __device__ __forceinline__

DEVI float b2f(u16 u){ union{unsigned int i; float f;} v; v.i=(unsigned int)u<<16; return v.f; }
DEVI u16 f2b(float f){ union{unsigned int i; float f;} v; v.f=f;
    unsigned int r=(v.i+0x7FFFu+((v.i>>16)&1u))>>16; return (u16)r; }

DEVI void gload_lds16(const u16* g, u16* l){
    __builtin_amdgcn_global_load_lds((__attribute__((address_space(1))) void*)g,
                                     (__attribute__((address_space(3))) void*)l,
                                     16, 0, 0);
}

// ---------------------------------------------------------------------------
// fp32 -> bf16 elementwise (X ingest). 4 elems/thread.
// ---------------------------------------------------------------------------
__global__ __launch_bounds__(256)
void cvt_bf16(const float* __restrict__ in, u16* __restrict__ out)
{
    const int i = (blockIdx.x * 256 + threadIdx.x) * 4;
    float4 v = *(const float4*)&in[i];
    ushort4 o;
    o.x = f2b(v.x); o.y = f2b(v.y); o.z = f2b(v.z); o.w = f2b(v.w);
    *(ushort4*)&out[i] = o;
}

// ---------------------------------------------------------------------------
// fp32 [R,C] -> bf16 [C,R] transpose (weight ingest). 64x64 LDS tiles.
// ---------------------------------------------------------------------------
__global__ __launch_bounds__(256)
void cvt_transpose(const float* __restrict__ in, u16* __restrict__ out, int R, int C)
{
    __shared__ __align__(16) u16 tile[64*72];
    const int rb = blockIdx.x*64, cb = blockIdx.y*64;
    const int t = threadIdx.x;
    const int r = t >> 3, c0 = (t & 7) * 8;
    #pragma unroll
    for (int rr = 0; rr < 2; rr++) {
        const int row = r + rr*32;
        float4 a = *(const float4*)&in[(long)(rb + row)*C + cb + c0];
        float4 b = *(const float4*)&in[(long)(rb + row)*C + cb + c0 + 4];
        u16* tp = &tile[row*72 + c0];
        tp[0]=f2b(a.x); tp[1]=f2b(a.y); tp[2]=f2b(a.z); tp[3]=f2b(a.w);
        tp[4]=f2b(b.x); tp[5]=f2b(b.y); tp[6]=f2b(b.z); tp[7]=f2b(b.w);
    }
    __syncthreads();
    #pragma unroll
    for (int rr = 0; rr < 2; rr++) {
        const int cr = r + rr*32;
        u16 tmp[8];
        #pragma unroll
        for (int j = 0; j < 8; j++) tmp[j] = tile[(c0 + j)*72 + cr];
        *(uint4*)&out[(long)(cb + cr)*R + rb + c0] = *(uint4*)tmp;
    }
}

// ---------------------------------------------------------------------------
// GEMM: C[M,N] = A[M,K] @ Bt[N,K]^T + bias. bf16 in/out, fp32 accum.
// Tile BM x 128, BK=64 (two 32-wide panels). 4 waves.
// EPI: 0 = bias, 1 = bias+residual, 2 = bias+tanh-GELU,
//      3 = QKV split: cols<2048 -> C row-major (width 2048),
//          cols>=2048 (V) -> C2 = VT[b*16+h][d][tok] transposed.
// ---------------------------------------------------------------------------
template<int EPI, int BM>
__global__ __launch_bounds__(256)
void gemm_bt(const u16* __restrict__ A, const u16* __restrict__ Bt,
             const float* __restrict__ bias, const u16* __restrict__ Res,
             u16* __restrict__ C, u16* __restrict__ C2, int M, int N, int K)
{
    constexpr int RM = BM / 32;
    constexpr int NA = (BM / 16) * 2 / 4;
    __shared__ __align__(16) u16 As[BM*64];
    __shared__ __align__(16) u16 Bs[128*64];
    const int tid  = threadIdx.x;
    const int wave = tid >> 6, lane = tid & 63;
    const int tm = blockIdx.x * BM, tn = blockIdx.y * 128;

    const int rs = lane >> 2, cs = (lane & 3) * 8;
    const u16* gA[NA]; u16* lA[NA];
    #pragma unroll
    for (int i = 0; i < NA; i++) {
        const int c = wave + i*4;
        const int p = c / (BM/16), rb = c % (BM/16);
        gA[i] = A + (long)(tm + rb*16 + rs)*K + p*32 + cs;
        lA[i] = As + p*(BM*32) + rb*512;
    }
    const u16* gB[4]; u16* lB[4];
    #pragma unroll
    for (int i = 0; i < 4; i++) {
        const int c = wave + i*4;
        const int p = c >> 3, rb = c & 7;
        gB[i] = Bt + (long)(tn + rb*16 + rs)*K + p*32 + cs;
        lB[i] = Bs + p*(128*32) + rb*512;
    }

    const int wm = (wave >> 1) * (BM/2), wn = (wave & 1) * 64;
    const int fr = lane & 15, fq = lane >> 4;

    f32x4 acc[RM][4] = {};
    for (int k0 = 0; k0 < K; k0 += 64) {
        __syncthreads();
        #pragma unroll
        for (int i = 0; i < NA; i++) gload_lds16(gA[i] + k0, lA[i]);
        #pragma unroll
        for (int i = 0; i < 4; i++)  gload_lds16(gB[i] + k0, lB[i]);
        __syncthreads();
        #pragma unroll
        for (int p = 0; p < 2; p++) {
            bf16x8 af[RM], bfr[4];
            #pragma unroll
            for (int i = 0; i < RM; i++)
                af[i]  = *(const bf16x8*)&As[p*(BM*32) + (wm + i*16 + fr)*32 + fq*8];
            #pragma unroll
            for (int j = 0; j < 4; j++)
                bfr[j] = *(const bf16x8*)&Bs[p*(128*32) + (wn + j*16 + fr)*32 + fq*8];
            #pragma unroll
            for (int i = 0; i < RM; i++)
                #pragma unroll
                for (int j = 0; j < 4; j++)
                    acc[i][j] = __builtin_amdgcn_mfma_f32_16x16x32_bf16(af[i], bfr[j], acc[i][j], 0, 0, 0);
        }
    }

    #pragma unroll
    for (int i = 0; i < RM; i++) {
        const int row = tm + wm + i*16 + fq*4;
        #pragma unroll
        for (int j = 0; j < 4; j++) {
            const int col = tn + wn + j*16 + fr;
            const float bv = bias[col];
            if (EPI == 3 && col >= 2048) {
                // V part -> VT[(b*16+h)][d][tok], 4 consecutive toks = 8B store
                const int hh = (col - 2048) >> 6, dd = (col - 2048) & 63;
                const int batch = row >> 11, tok = row & 2047;
                u16 pk[4];
                #pragma unroll
                for (int r = 0; r < 4; r++) pk[r] = f2b(acc[i][j][r] + bv);
                *(uint2*)&C2[((long)(batch*16 + hh)*64 + dd)*2048 + tok] = *(uint2*)pk;
            } else {
                const int cw = (EPI == 3) ? 2048 : N;
                #pragma unroll
                for (int r = 0; r < 4; r++) {
                    float v = acc[i][j][r] + bv;
                    const long idx = (long)(row + r)*cw + col;
                    if (EPI == 1) v += b2f(Res[idx]);
                    if (EPI == 2) {
                        const float u = v + 0.044715f*v*v*v;
                        const float t = exp2f(u * 2.302208f);
                        v = v * t * __builtin_amdgcn_rcpf(t + 1.f);
                    }
                    C[idx] = f2b(v);
                }
            }
        }
    }
}

// ---------------------------------------------------------------------------
// Flash attention v4, causal. block = (qtile64, head, batch); 4 waves x 16 q.
// 128-key tiles. All staging via global_load_lds (GEMM-style 32-wide panels,
// no VALU unpack). V pre-transposed globally (VT). Q frags loaded from global.
// Scale 1/8 folded into exp2 constant. S^T = K Q^T, O^T = V^T P^T (per-lane
// softmax state, no cross-lane broadcasts). LDS exactly 40 KB -> 4 blocks/CU.
// LPT: qt = 31 - blockIdx.x (heaviest first).
// ---------------------------------------------------------------------------
__global__ __launch_bounds__(256)
void attn_kernel(const u16* __restrict__ QK, const u16* __restrict__ VT,
                 u16* __restrict__ O)
{
    constexpr float CS = 0.18033688011112042f;   // 0.125 * log2(e)
    __shared__ __align__(16) u16 Ks[2*128*32];   // [d-panel][128 key][32 d]
    __shared__ __align__(16) u16 Vs[4*64*32];    // [key-panel][64 d][32 key]
    __shared__ __align__(16) u16 Ps[4*16*64];    // per-wave P, XOR-swizzled

    const int tid = threadIdx.x, wave = tid >> 6, lane = tid & 63;
    const int qt = 31 - blockIdx.x, h = blockIdx.y, b = blockIdx.z;
    const int fr = lane & 15, fq = lane >> 4;
    const long qkbase = (long)b*2048*2048;           // QK rows for this batch
    const long vtbase = (long)(b*16 + h)*64*2048;    // VT rows for this (b,h)

    // Q B-fragments straight from global: q-row = wave*16+fr, d = ks*32+fq*8
    bf16x8 bq[2];
    #pragma unroll
    for (int ks = 0; ks < 2; ks++)
        bq[ks] = *(const bf16x8*)&QK[qkbase + (long)(qt*64 + wave*16 + fr)*2048
                                     + h*64 + ks*32 + fq*8];

    const int q_glob = qt*64 + wave*16 + fr;
    const int q_wmin = qt*64 + wave*16;
    f32x4 o[4] = {};
    float m_i = -1e30f, l_i = 0.f;
    const int nkt = (qt >> 1) + 1;
    const int rs = lane >> 2, cs2 = (lane & 3) * 8;
    const int sw = (fr & 7) * 8;                 // P XOR swizzle

    for (int kt = 0; kt < nkt; kt++) {
        const int k0 = kt * 128;
        __syncthreads();
        // K: 2 d-panels x 8 rowgroups; V: 4 key-panels x 4 dgroups
        #pragma unroll
        for (int i = 0; i < 4; i++) {
            const int c = wave + i*4;
            const int kp = c >> 3, krb = c & 7;
            gload_lds16(QK + qkbase + (long)(k0 + krb*16 + rs)*2048
                           + 1024 + h*64 + kp*32 + cs2,
                        Ks + kp*4096 + krb*512);
            const int vp = c & 3, vrb = c >> 2;
            gload_lds16(VT + vtbase + (long)(vrb*16 + rs)*2048 + k0 + vp*32 + cs2,
                        Vs + vp*2048 + vrb*512);
        }
        __syncthreads();

        // S^T = K Q^T : 8 key-tiles x 16 q
        f32x4 st[8];
        #pragma unroll
        for (int mt = 0; mt < 8; mt++) st[mt] = (f32x4){0.f,0.f,0.f,0.f};
        #pragma unroll
        for (int mt = 0; mt < 8; mt++)
            #pragma unroll
            for (int ks = 0; ks < 2; ks++) {
                bf16x8 ak = *(const bf16x8*)&Ks[ks*4096 + (mt*16 + fr)*32 + fq*8];
                st[mt] = __builtin_amdgcn_mfma_f32_16x16x32_bf16(ak, bq[ks], st[mt], 0, 0, 0);
            }

        // mask (only near diagonal) + per-lane softmax (raw scores, CS scale)
        float mx = -1e30f;
        if (k0 + 127 > q_wmin) {
            #pragma unroll
            for (int mt = 0; mt < 8; mt++)
                #pragma unroll
                for (int r = 0; r < 4; r++) {
                    const int key = k0 + mt*16 + fq*4 + r;
                    float v = st[mt][r];
                    if (key > q_glob) v = -1e30f;
                    st[mt][r] = v;
                    mx = fmaxf(mx, v);
                }
        } else {
            #pragma unroll
            for (int mt = 0; mt < 8; mt++)
                #pragma unroll
                for (int r = 0; r < 4; r++) mx = fmaxf(mx, st[mt][r]);
        }
        mx = fmaxf(mx, __shfl_xor(mx, 16, 64));
        mx = fmaxf(mx, __shfl_xor(mx, 32, 64));
        const float mnew  = fmaxf(m_i, mx);
        const float alpha = exp2f((m_i - mnew) * CS);
        float ps = 0.f;
        #pragma unroll
        for (int mt = 0; mt < 8; mt++)
            #pragma unroll
            for (int r = 0; r < 4; r++) {
                const float p = exp2f((st[mt][r] - mnew) * CS);
                st[mt][r] = p; ps += p;
            }
        ps += __shfl_xor(ps, 16, 64);
        ps += __shfl_xor(ps, 32, 64);
        l_i = l_i * alpha + ps;
        m_i = mnew;

        #pragma unroll
        for (int dt = 0; dt < 4; dt++)
            #pragma unroll
            for (int r = 0; r < 4; r++) o[dt][r] *= alpha;

        // PV per 64-key half: P -> swizzled LDS, O^T += V^T P^T
        u16* pw = &Ps[wave * 1024];
        #pragma unroll
        for (int half = 0; half < 2; half++) {
            #pragma unroll
            for (int mt2 = 0; mt2 < 4; mt2++)
                #pragma unroll
                for (int d = 0; d < 2; d++) {
                    const int mt = half*4 + mt2;
                    const unsigned pk = (unsigned)f2b(st[mt][2*d]) |
                                        ((unsigned)f2b(st[mt][2*d+1]) << 16);
                    *(unsigned*)&pw[fr*64 + ((mt2*16 + fq*4 + 2*d) ^ sw)] = pk;
                }
            __asm__ volatile("" ::: "memory");
            bf16x8 bp[2];
            #pragma unroll
            for (int kk = 0; kk < 2; kk++)
                bp[kk] = *(const bf16x8*)&pw[fr*64 + ((kk*32 + fq*8) ^ sw)];
            #pragma unroll
            for (int dt = 0; dt < 4; dt++) {
                #pragma unroll
                for (int kk = 0; kk < 2; kk++) {
                    bf16x8 av = *(const bf16x8*)&Vs[(half*2 + kk)*2048
                                                    + (dt*16 + fr)*32 + fq*8];
                    o[dt] = __builtin_amdgcn_mfma_f32_16x16x32_bf16(av, bp[kk], o[dt], 0, 0, 0);
                }
            }
            __asm__ volatile("" ::: "memory");
        }
    }

    // epilogue: lane fr owns q-row; pack 4 cols -> 8B stores
    const float rl = __builtin_amdgcn_rcpf(l_i);
    const long orow = (long)b*2048 + qt*64 + wave*16 + fr;
    #pragma unroll
    for (int dt = 0; dt < 4; dt++) {
        u16 pk[4];
        #pragma unroll
        for (int r = 0; r < 4; r++) pk[r] = f2b(o[dt][r] * rl);
        *(uint2*)&O[orow*1024 + h*64 + dt*16 + fq*4] = *(uint2*)pk;
    }
}

// ---------------------------------------------------------------------------
// LayerNorm over 1024 cols; bf16 in, fp32 gamma/beta; OUTF32 selects output.
// ---------------------------------------------------------------------------
template<int OUTF32>
__global__ __launch_bounds__(256)
void ln_kernel(const u16* __restrict__ X, const float* __restrict__ G,
               const float* __restrict__ B, void* __restrict__ Yv)
{
    __shared__ float red[8];
    const int tid = threadIdx.x;
    const long row = blockIdx.x;
    const u16* x = X + row*1024;
    ushort4 u = *(const ushort4*)&x[tid*4];
    const float v0 = b2f(u.x), v1 = b2f(u.y), v2 = b2f(u.z), v3 = b2f(u.w);
    float s = v0+v1+v2+v3;
    float q = v0*v0+v1*v1+v2*v2+v3*v3;
    #pragma unroll
    for (int off = 32; off >= 1; off >>= 1) {
        s += __shfl_xor(s, off, 64);
        q += __shfl_xor(q, off, 64);
    }
    const int wv = tid >> 6;
    if ((tid & 63) == 0) { red[wv*2] = s; red[wv*2+1] = q; }
    __syncthreads();
    s = red[0]+red[2]+red[4]+red[6];
    q = red[1]+red[3]+red[5]+red[7];
    const float mu = s * (1.f/1024.f);
    const float rstd = rsqrtf(fmaxf(q*(1.f/1024.f) - mu*mu, 0.f) + 1e-5f);
    float4 g4 = *(const float4*)&G[tid*4];
    float4 b4 = *(const float4*)&B[tid*4];
    const float y0 = (v0-mu)*rstd*g4.x + b4.x;
    const float y1 = (v1-mu)*rstd*g4.y + b4.y;
    const float y2 = (v2-mu)*rstd*g4.z + b4.z;
    const float y3 = (v3-mu)*rstd*g4.w + b4.w;
    if (OUTF32) {
        float4 o = make_float4(y0, y1, y2, y3);
        *(float4*)&((float*)Yv)[row*1024 + tid*4] = o;
    } else {
        ushort4 o;
        o.x = f2b(y0); o.y = f2b(y1); o.z = f2b(y2); o.w = f2b(y3);
        *(ushort4*)&((u16*)Yv)[row*1024 + tid*4] = o;
    }
}

// ---------------------------------------------------------------------------
// Workspace (48 MiB of d_ws + d_out as W1T/W2T scratch), liveness-audited:
//   Xbf [0,8) | WqkvT [8,14) | WoT [14,16) | QK [16,32) | VT [32,40) |
//   AO [40,48) | S1 [16,24) after attn | H1 [0,8) after LN1 |
//   Gbuf [8,40) FF1..FF2 | S2 [40,48) | W1T/W2T in d_out (dead before LN2)
// ---------------------------------------------------------------------------
extern "C" void kernel_launch(void* const* d_in, const int* in_sizes, int n_in,
                              void* d_out, int out_size, void* d_ws, size_t ws_size,
                              hipStream_t stream)
{
    const float* X    = (const float*)d_in[0];
    const float* Wqkv = (const float*)d_in[1];
    const float* bqkv = (const float*)d_in[2];
    const float* Wo   = (const float*)d_in[3];
    const float* bo   = (const float*)d_in[4];
    const float* W1   = (const float*)d_in[5];
    const float* b1   = (const float*)d_in[6];
    const float* W2   = (const float*)d_in[7];
    const float* b2   = (const float*)d_in[8];
    const float* g1   = (const float*)d_in[9];
    const float* be1  = (const float*)d_in[10];
    const float* g2   = (const float*)d_in[11];
    const float* be2  = (const float*)d_in[12];
    float* out = (float*)d_out;

    char* ws = (char*)d_ws;
    u16* Xbf   = (u16*)(ws + 0);
    u16* WqkvT = (u16*)(ws + 8388608);
    u16* WoT   = (u16*)(ws + 14680064);
    u16* QK    = (u16*)(ws + 16777216);        // 4096 x 2048
    u16* VT    = (u16*)(ws + 33554432);        // [2*16][64][2048]
    u16* AO    = (u16*)(ws + 41943040);
    u16* S1    = (u16*)(ws + 16777216);
    u16* H1    = (u16*)(ws + 0);
    u16* Gbuf  = (u16*)(ws + 8388608);
    u16* S2    = (u16*)(ws + 41943040);
    u16* W1T   = (u16*)d_out;
    u16* W2T   = (u16*)d_out + 4194304;

    cvt_bf16<<<4096, 256, 0, stream>>>(X, Xbf);
    cvt_transpose<<<dim3(16, 48), 256, 0, stream>>>(Wqkv, WqkvT, 1024, 3072);
    cvt_transpose<<<dim3(16, 16), 256, 0, stream>>>(Wo,   WoT,   1024, 1024);
    cvt_transpose<<<dim3(16, 64), 256, 0, stream>>>(W1,   W1T,   1024, 4096);
    cvt_transpose<<<dim3(64, 16), 256, 0, stream>>>(W2,   W2T,   4096, 1024);

    gemm_bt<3,128><<<dim3(32, 24), 256, 0, stream>>>(Xbf, WqkvT, bqkv, nullptr, QK, VT, 4096, 3072, 1024);
    attn_kernel<<<dim3(32, 16, 2), 256, 0, stream>>>(QK, VT, AO);
    gemm_bt<1,64><<<dim3(64, 8), 256, 0, stream>>>(AO, WoT, bo, Xbf, S1, nullptr, 4096, 1024, 1024);
    ln_kernel<0><<<4096, 256, 0, stream>>>(S1, g1, be1, H1);
    gemm_bt<2,128><<<dim3(32, 32), 256, 0, stream>>>(H1, W1T, b1, nullptr, Gbuf, nullptr, 4096, 4096, 1024);
    gemm_bt<1,64><<<dim3(64, 8), 256, 0, stream>>>(Gbuf, W2T, b2, H1, S2, nullptr, 4096, 1024, 4096);
    ln_kernel<1><<<4096, 256, 0, stream>>>(S2, g2, be2, out);
}

// Round 8
// 399.600 us; speedup vs baseline: 1.0515x; 1.0198x over previous
//
#include <hip/hip_runtime.h>
#include <cmath>

typedef unsigned short u16;
typedef __bf16 bf16x8 __attribute__((ext_vector_type(8)));
typedef float f32x4 __attribute__((ext_vector_type(4)));

#define DEVI __device__ __forceinline__

DEVI float b2f(u16 u){ union{unsigned int i; float f;} v; v.i=(unsigned int)u<<16; return v.f; }
DEVI u16 f2b(float f){ union{unsigned int i; float f;} v; v.f=f;
    unsigned int r=(v.i+0x7FFFu+((v.i>>16)&1u))>>16; return (u16)r; }

DEVI void gload_lds16(const u16* g, u16* l){
    __builtin_amdgcn_global_load_lds((__attribute__((address_space(1))) void*)g,
                                     (__attribute__((address_space(3))) void*)l,
                                     16, 0, 0);
}

// ---------------------------------------------------------------------------
// fp32 -> bf16 elementwise (X ingest). 4 elems/thread.
// ---------------------------------------------------------------------------
__global__ __launch_bounds__(256)
void cvt_bf16(const float* __restrict__ in, u16* __restrict__ out)
{
    const int i = (blockIdx.x * 256 + threadIdx.x) * 4;
    float4 v = *(const float4*)&in[i];
    ushort4 o;
    o.x = f2b(v.x); o.y = f2b(v.y); o.z = f2b(v.z); o.w = f2b(v.w);
    *(ushort4*)&out[i] = o;
}

// ---------------------------------------------------------------------------
// fp32 [R,C] -> bf16 [C,R] transpose (weight ingest). 64x64 LDS tiles.
// ---------------------------------------------------------------------------
__global__ __launch_bounds__(256)
void cvt_transpose(const float* __restrict__ in, u16* __restrict__ out, int R, int C)
{
    __shared__ __align__(16) u16 tile[64*72];
    const int rb = blockIdx.x*64, cb = blockIdx.y*64;
    const int t = threadIdx.x;
    const int r = t >> 3, c0 = (t & 7) * 8;
    #pragma unroll
    for (int rr = 0; rr < 2; rr++) {
        const int row = r + rr*32;
        float4 a = *(const float4*)&in[(long)(rb + row)*C + cb + c0];
        float4 b = *(const float4*)&in[(long)(rb + row)*C + cb + c0 + 4];
        u16* tp = &tile[row*72 + c0];
        tp[0]=f2b(a.x); tp[1]=f2b(a.y); tp[2]=f2b(a.z); tp[3]=f2b(a.w);
        tp[4]=f2b(b.x); tp[5]=f2b(b.y); tp[6]=f2b(b.z); tp[7]=f2b(b.w);
    }
    __syncthreads();
    #pragma unroll
    for (int rr = 0; rr < 2; rr++) {
        const int cr = r + rr*32;
        u16 tmp[8];
        #pragma unroll
        for (int j = 0; j < 8; j++) tmp[j] = tile[(c0 + j)*72 + cr];
        *(uint4*)&out[(long)(cb + cr)*R + rb + c0] = *(uint4*)tmp;
    }
}

// ---------------------------------------------------------------------------
// GEMM: C[M,N] = A[M,K] @ Bt[N,K]^T + bias. bf16 in/out, fp32 accum.
// Tile BM x 128, BK=64 (two 32-wide panels). 4 waves.
// EPI: 0 = bias, 1 = bias+residual, 2 = bias+tanh-GELU,
//      3 = QKV split: cols<2048 -> C row-major (width 2048),
//          cols>=2048 (V) -> C2 = VT[b*16+h][d][tok] transposed.
// ---------------------------------------------------------------------------
template<int EPI, int BM>
__global__ __launch_bounds__(256)
void gemm_bt(const u16* __restrict__ A, const u16* __restrict__ Bt,
             const float* __restrict__ bias, const u16* __restrict__ Res,
             u16* __restrict__ C, u16* __restrict__ C2, int M, int N, int K)
{
    constexpr int RM = BM / 32;
    constexpr int NA = (BM / 16) * 2 / 4;
    __shared__ __align__(16) u16 As[BM*64];
    __shared__ __align__(16) u16 Bs[128*64];
    const int tid  = threadIdx.x;
    const int wave = tid >> 6, lane = tid & 63;
    const int tm = blockIdx.x * BM, tn = blockIdx.y * 128;

    const int rs = lane >> 2, cs = (lane & 3) * 8;
    const u16* gA[NA]; u16* lA[NA];
    #pragma unroll
    for (int i = 0; i < NA; i++) {
        const int c = wave + i*4;
        const int p = c / (BM/16), rb = c % (BM/16);
        gA[i] = A + (long)(tm + rb*16 + rs)*K + p*32 + cs;
        lA[i] = As + p*(BM*32) + rb*512;
    }
    const u16* gB[4]; u16* lB[4];
    #pragma unroll
    for (int i = 0; i < 4; i++) {
        const int c = wave + i*4;
        const int p = c >> 3, rb = c & 7;
        gB[i] = Bt + (long)(tn + rb*16 + rs)*K + p*32 + cs;
        lB[i] = Bs + p*(128*32) + rb*512;
    }

    const int wm = (wave >> 1) * (BM/2), wn = (wave & 1) * 64;
    const int fr = lane & 15, fq = lane >> 4;

    f32x4 acc[RM][4] = {};
    for (int k0 = 0; k0 < K; k0 += 64) {
        __syncthreads();
        #pragma unroll
        for (int i = 0; i < NA; i++) gload_lds16(gA[i] + k0, lA[i]);
        #pragma unroll
        for (int i = 0; i < 4; i++)  gload_lds16(gB[i] + k0, lB[i]);
        __syncthreads();
        #pragma unroll
        for (int p = 0; p < 2; p++) {
            bf16x8 af[RM], bfr[4];
            #pragma unroll
            for (int i = 0; i < RM; i++)
                af[i]  = *(const bf16x8*)&As[p*(BM*32) + (wm + i*16 + fr)*32 + fq*8];
            #pragma unroll
            for (int j = 0; j < 4; j++)
                bfr[j] = *(const bf16x8*)&Bs[p*(128*32) + (wn + j*16 + fr)*32 + fq*8];
            #pragma unroll
            for (int i = 0; i < RM; i++)
                #pragma unroll
                for (int j = 0; j < 4; j++)
                    acc[i][j] = __builtin_amdgcn_mfma_f32_16x16x32_bf16(af[i], bfr[j], acc[i][j], 0, 0, 0);
        }
    }

    #pragma unroll
    for (int i = 0; i < RM; i++) {
        const int row = tm + wm + i*16 + fq*4;
        #pragma unroll
        for (int j = 0; j < 4; j++) {
            const int col = tn + wn + j*16 + fr;
            const float bv = bias[col];
            if (EPI == 3 && col >= 2048) {
                const int hh = (col - 2048) >> 6, dd = (col - 2048) & 63;
                const int batch = row >> 11, tok = row & 2047;
                u16 pk[4];
                #pragma unroll
                for (int r = 0; r < 4; r++) pk[r] = f2b(acc[i][j][r] + bv);
                *(uint2*)&C2[((long)(batch*16 + hh)*64 + dd)*2048 + tok] = *(uint2*)pk;
            } else {
                const int cw = (EPI == 3) ? 2048 : N;
                #pragma unroll
                for (int r = 0; r < 4; r++) {
                    float v = acc[i][j][r] + bv;
                    const long idx = (long)(row + r)*cw + col;
                    if (EPI == 1) v += b2f(Res[idx]);
                    if (EPI == 2) {
                        const float u = v + 0.044715f*v*v*v;
                        const float t = exp2f(u * 2.302208f);
                        v = v * t * __builtin_amdgcn_rcpf(t + 1.f);
                    }
                    C[idx] = f2b(v);
                }
            }
        }
    }
}

// ---------------------------------------------------------------------------
// Flash attention v5, causal. block = (qtile64, head, batch); 4 waves x 16 q.
// 64-key tiles, DOUBLE-BUFFERED staging: one barrier per iteration; loads for
// tile kt+1 issued right after the barrier, overlapping compute on tile kt.
// All staging via global_load_lds. V pre-transposed globally (VT). S^T = K Q^T,
// O^T = V^T P^T (per-lane softmax state). LDS 40 KB -> 4 blocks/CU.
// LPT: qt = 31 - blockIdx.x.
// ---------------------------------------------------------------------------
__global__ __launch_bounds__(256)
void attn_kernel(const u16* __restrict__ QK, const u16* __restrict__ VT,
                 u16* __restrict__ O)
{
    constexpr float CS = 0.18033688011112042f;   // 0.125 * log2(e)
    __shared__ __align__(16) u16 Ks[2][4096];    // [buf][dpanel*2048 + key*32 + d]
    __shared__ __align__(16) u16 Vs[2][4096];    // [buf][kpanel*2048 + d*32 + key]
    __shared__ __align__(16) u16 Ps[4][1024];    // per-wave P, XOR-swizzled

    const int tid = threadIdx.x, wave = tid >> 6, lane = tid & 63;
    const int qt = 31 - blockIdx.x, h = blockIdx.y, b = blockIdx.z;
    const int fr = lane & 15, fq = lane >> 4;
    const long qkbase = (long)b*2048*2048;
    const long vtbase = (long)(b*16 + h)*64*2048;

    // Q B-fragments straight from global
    bf16x8 bq[2];
    #pragma unroll
    for (int ks = 0; ks < 2; ks++)
        bq[ks] = *(const bf16x8*)&QK[qkbase + (long)(qt*64 + wave*16 + fr)*2048
                                     + h*64 + ks*32 + fq*8];

    const int q_glob = qt*64 + wave*16 + fr;
    const int q_wmin = qt*64 + wave*16;
    f32x4 o[4] = {};
    float m_i = -1e30f, l_i = 0.f;
    const int nkt = qt + 1;                      // 64-key tiles
    const int rs = lane >> 2, cs2 = (lane & 3) * 8;
    const int sw = (fr & 7) * 8;

    // stage tile (64 keys) into buffer bf: 2 K-chunks + 2 V-chunks per wave
    #define ISSUE(bf, k0)                                                      \
        _Pragma("unroll")                                                      \
        for (int i = 0; i < 2; i++) {                                          \
            const int c = wave + i*4;                                          \
            const int kp = c >> 2, krb = c & 3;                                \
            gload_lds16(QK + qkbase + (long)((k0) + krb*16 + rs)*2048          \
                           + 1024 + h*64 + kp*32 + cs2,                        \
                        &Ks[bf][kp*2048 + krb*512]);                           \
            const int vp = c & 1, vrb = c >> 1;                                \
            gload_lds16(VT + vtbase + (long)(vrb*16 + rs)*2048                 \
                           + (k0) + vp*32 + cs2,                               \
                        &Vs[bf][vp*2048 + vrb*512]);                           \
        }

    ISSUE(0, 0)

    for (int kt = 0; kt < nkt; kt++) {
        const int k0 = kt * 64;
        const int cur = kt & 1;
        __syncthreads();          // drains my in-flight loads (tile kt); rendezvous
        if (kt + 1 < nkt) { ISSUE(cur ^ 1, k0 + 64) }   // prefetch overlaps compute

        // S^T = K Q^T : 4 key-tiles x 16 q
        f32x4 st[4];
        #pragma unroll
        for (int mt = 0; mt < 4; mt++) st[mt] = (f32x4){0.f,0.f,0.f,0.f};
        #pragma unroll
        for (int mt = 0; mt < 4; mt++)
            #pragma unroll
            for (int ks = 0; ks < 2; ks++) {
                bf16x8 ak = *(const bf16x8*)&Ks[cur][ks*2048 + (mt*16 + fr)*32 + fq*8];
                st[mt] = __builtin_amdgcn_mfma_f32_16x16x32_bf16(ak, bq[ks], st[mt], 0, 0, 0);
            }

        // mask (only when tile crosses diagonal) + per-lane softmax
        float mx = -1e30f;
        if (k0 + 63 > q_wmin) {
            #pragma unroll
            for (int mt = 0; mt < 4; mt++)
                #pragma unroll
                for (int r = 0; r < 4; r++) {
                    const int key = k0 + mt*16 + fq*4 + r;
                    float v = st[mt][r];
                    if (key > q_glob) v = -1e30f;
                    st[mt][r] = v;
                    mx = fmaxf(mx, v);
                }
        } else {
            #pragma unroll
            for (int mt = 0; mt < 4; mt++)
                #pragma unroll
                for (int r = 0; r < 4; r++) mx = fmaxf(mx, st[mt][r]);
        }
        mx = fmaxf(mx, __shfl_xor(mx, 16, 64));
        mx = fmaxf(mx, __shfl_xor(mx, 32, 64));
        const float mnew  = fmaxf(m_i, mx);
        const float alpha = exp2f((m_i - mnew) * CS);
        float ps = 0.f;
        #pragma unroll
        for (int mt = 0; mt < 4; mt++)
            #pragma unroll
            for (int r = 0; r < 4; r++) {
                const float p = exp2f((st[mt][r] - mnew) * CS);
                st[mt][r] = p; ps += p;
            }
        ps += __shfl_xor(ps, 16, 64);
        ps += __shfl_xor(ps, 32, 64);
        l_i = l_i * alpha + ps;
        m_i = mnew;

        #pragma unroll
        for (int dt = 0; dt < 4; dt++)
            #pragma unroll
            for (int r = 0; r < 4; r++) o[dt][r] *= alpha;

        // P -> swizzled wave-private LDS, then O^T += V^T P^T
        u16* pw = Ps[wave];
        #pragma unroll
        for (int mt = 0; mt < 4; mt++)
            #pragma unroll
            for (int d = 0; d < 2; d++) {
                const unsigned pk = (unsigned)f2b(st[mt][2*d]) |
                                    ((unsigned)f2b(st[mt][2*d+1]) << 16);
                *(unsigned*)&pw[fr*64 + ((mt*16 + fq*4 + 2*d) ^ sw)] = pk;
            }
        __asm__ volatile("" ::: "memory");
        bf16x8 bp[2];
        #pragma unroll
        for (int kk = 0; kk < 2; kk++)
            bp[kk] = *(const bf16x8*)&pw[fr*64 + ((kk*32 + fq*8) ^ sw)];
        #pragma unroll
        for (int dt = 0; dt < 4; dt++)
            #pragma unroll
            for (int kk = 0; kk < 2; kk++) {
                bf16x8 av = *(const bf16x8*)&Vs[cur][kk*2048 + (dt*16 + fr)*32 + fq*8];
                o[dt] = __builtin_amdgcn_mfma_f32_16x16x32_bf16(av, bp[kk], o[dt], 0, 0, 0);
            }
        __asm__ volatile("" ::: "memory");
    }
    #undef ISSUE

    // epilogue: lane fr owns q-row; pack 4 cols -> 8B stores
    const float rl = __builtin_amdgcn_rcpf(l_i);
    const long orow = (long)b*2048 + qt*64 + wave*16 + fr;
    #pragma unroll
    for (int dt = 0; dt < 4; dt++) {
        u16 pk[4];
        #pragma unroll
        for (int r = 0; r < 4; r++) pk[r] = f2b(o[dt][r] * rl);
        *(uint2*)&O[orow*1024 + h*64 + dt*16 + fq*4] = *(uint2*)pk;
    }
}

// ---------------------------------------------------------------------------
// LayerNorm over 1024 cols; bf16 in, fp32 gamma/beta; OUTF32 selects output.
// ---------------------------------------------------------------------------
template<int OUTF32>
__global__ __launch_bounds__(256)
void ln_kernel(const u16* __restrict__ X, const float* __restrict__ G,
               const float* __restrict__ B, void* __restrict__ Yv)
{
    __shared__ float red[8];
    const int tid = threadIdx.x;
    const long row = blockIdx.x;
    const u16* x = X + row*1024;
    ushort4 u = *(const ushort4*)&x[tid*4];
    const float v0 = b2f(u.x), v1 = b2f(u.y), v2 = b2f(u.z), v3 = b2f(u.w);
    float s = v0+v1+v2+v3;
    float q = v0*v0+v1*v1+v2*v2+v3*v3;
    #pragma unroll
    for (int off = 32; off >= 1; off >>= 1) {
        s += __shfl_xor(s, off, 64);
        q += __shfl_xor(q, off, 64);
    }
    const int wv = tid >> 6;
    if ((tid & 63) == 0) { red[wv*2] = s; red[wv*2+1] = q; }
    __syncthreads();
    s = red[0]+red[2]+red[4]+red[6];
    q = red[1]+red[3]+red[5]+red[7];
    const float mu = s * (1.f/1024.f);
    const float rstd = rsqrtf(fmaxf(q*(1.f/1024.f) - mu*mu, 0.f) + 1e-5f);
    float4 g4 = *(const float4*)&G[tid*4];
    float4 b4 = *(const float4*)&B[tid*4];
    const float y0 = (v0-mu)*rstd*g4.x + b4.x;
    const float y1 = (v1-mu)*rstd*g4.y + b4.y;
    const float y2 = (v2-mu)*rstd*g4.z + b4.z;
    const float y3 = (v3-mu)*rstd*g4.w + b4.w;
    if (OUTF32) {
        float4 o = make_float4(y0, y1, y2, y3);
        *(float4*)&((float*)Yv)[row*1024 + tid*4] = o;
    } else {
        ushort4 o;
        o.x = f2b(y0); o.y = f2b(y1); o.z = f2b(y2); o.w = f2b(y3);
        *(ushort4*)&((u16*)Yv)[row*1024 + tid*4] = o;
    }
}

// ---------------------------------------------------------------------------
// Workspace (48 MiB of d_ws + d_out as W1T/W2T scratch), liveness-audited:
//   Xbf [0,8) | WqkvT [8,14) | WoT [14,16) | QK [16,32) | VT [32,40) |
//   AO [40,48) | S1 [16,24) after attn | H1 [0,8) after LN1 |
//   Gbuf [8,40) FF1..FF2 | S2 [40,48) | W1T/W2T in d_out (dead before LN2)
// ---------------------------------------------------------------------------
extern "C" void kernel_launch(void* const* d_in, const int* in_sizes, int n_in,
                              void* d_out, int out_size, void* d_ws, size_t ws_size,
                              hipStream_t stream)
{
    const float* X    = (const float*)d_in[0];
    const float* Wqkv = (const float*)d_in[1];
    const float* bqkv = (const float*)d_in[2];
    const float* Wo   = (const float*)d_in[3];
    const float* bo   = (const float*)d_in[4];
    const float* W1   = (const float*)d_in[5];
    const float* b1   = (const float*)d_in[6];
    const float* W2   = (const float*)d_in[7];
    const float* b2   = (const float*)d_in[8];
    const float* g1   = (const float*)d_in[9];
    const float* be1  = (const float*)d_in[10];
    const float* g2   = (const float*)d_in[11];
    const float* be2  = (const float*)d_in[12];
    float* out = (float*)d_out;

    char* ws = (char*)d_ws;
    u16* Xbf   = (u16*)(ws + 0);
    u16* WqkvT = (u16*)(ws + 8388608);
    u16* WoT   = (u16*)(ws + 14680064);
    u16* QK    = (u16*)(ws + 16777216);        // 4096 x 2048
    u16* VT    = (u16*)(ws + 33554432);        // [2*16][64][2048]
    u16* AO    = (u16*)(ws + 41943040);
    u16* S1    = (u16*)(ws + 16777216);
    u16* H1    = (u16*)(ws + 0);
    u16* Gbuf  = (u16*)(ws + 8388608);
    u16* S2    = (u16*)(ws + 41943040);
    u16* W1T   = (u16*)d_out;
    u16* W2T   = (u16*)d_out + 4194304;

    cvt_bf16<<<4096, 256, 0, stream>>>(X, Xbf);
    cvt_transpose<<<dim3(16, 48), 256, 0, stream>>>(Wqkv, WqkvT, 1024, 3072);
    cvt_transpose<<<dim3(16, 16), 256, 0, stream>>>(Wo,   WoT,   1024, 1024);
    cvt_transpose<<<dim3(16, 64), 256, 0, stream>>>(W1,   W1T,   1024, 4096);
    cvt_transpose<<<dim3(64, 16), 256, 0, stream>>>(W2,   W2T,   4096, 1024);

    gemm_bt<3,128><<<dim3(32, 24), 256, 0, stream>>>(Xbf, WqkvT, bqkv, nullptr, QK, VT, 4096, 3072, 1024);
    attn_kernel<<<dim3(32, 16, 2), 256, 0, stream>>>(QK, VT, AO);
    gemm_bt<1,64><<<dim3(64, 8), 256, 0, stream>>>(AO, WoT, bo, Xbf, S1, nullptr, 4096, 1024, 1024);
    ln_kernel<0><<<4096, 256, 0, stream>>>(S1, g1, be1, H1);
    gemm_bt<2,128><<<dim3(32, 32), 256, 0, stream>>>(H1, W1T, b1, nullptr, Gbuf, nullptr, 4096, 4096, 1024);
    gemm_bt<1,64><<<dim3(64, 8), 256, 0, stream>>>(Gbuf, W2T, b2, H1, S2, nullptr, 4096, 1024, 4096);
    ln_kernel<1><<<4096, 256, 0, stream>>>(S2, g2, be2, out);
}